// Round 1
// baseline (171.702 us; speedup 1.0000x reference)
//
#include <hip/hip_runtime.h>
#include <hip/hip_bf16.h>

#define NROWS 131072
#define KEXP 16
#define MPC 128
#define DIMD 64

typedef float f32x4 __attribute__((ext_vector_type(4)));
typedef short s16x8 __attribute__((ext_vector_type(8)));

#define L2E 1.4426950408889634f
#define LN2 0.6931471805599453f

static __device__ inline unsigned int b2u(__hip_bfloat162 h) {
    union { __hip_bfloat162 h; unsigned int u; } c;
    c.h = h;
    return c.u;
}

// prep: abf = bf16(a * log2e), eb = exp(b)
__global__ void prep_kernel(const float* __restrict__ a, const float* __restrict__ b,
                            short* __restrict__ abf, float* __restrict__ eb) {
    if (blockIdx.x < 128) {
        int i = (blockIdx.x * 256 + threadIdx.x) * 4;
        float4 v = *(const float4*)(a + i);
        __hip_bfloat162 p0 = __float22bfloat162_rn(make_float2(v.x * L2E, v.y * L2E));
        __hip_bfloat162 p1 = __float22bfloat162_rn(make_float2(v.z * L2E, v.w * L2E));
        uint2 u;
        u.x = b2u(p0);
        u.y = b2u(p1);
        *(uint2*)(abf + i) = u;
    } else {
        for (int r = threadIdx.x; r < KEXP * MPC; r += 256)
            eb[r] = __expf(b[r]);
    }
}

// Each block: 4 waves, wave w handles expert eg*4+w; block covers 128 rows (8 groups of 16).
// B-fragments (16 KB/expert) live in 64 VGPRs per wave. x staged to LDS per 16-row group
// in MFMA A-fragment order (conflict-free ds_read_b128), double-buffered.
__global__ __launch_bounds__(256, 3)
void moe_lse_kernel(const float* __restrict__ x, const float* __restrict__ s,
                    const short* __restrict__ abf, const float* __restrict__ ebp,
                    float* __restrict__ out) {
    __shared__ int4 xs4[2][128];  // 2 x 2KB: 16 rows x 64 d of bf16, fragment order

    const int tid  = threadIdx.x;
    const int w    = tid >> 6;
    const int l    = tid & 63;
    const int li   = l & 15;
    const int quad = l >> 4;

    const int bid    = blockIdx.x;
    const int eg     = bid & 3;
    const int rb     = bid >> 2;
    const int k      = eg * 4 + w;
    const int r_base = rb * 128;

    // persistent B fragments for this wave's expert: B[d][m], lane holds m=t*16+li, d=dc*32+quad*8..+7
    s16x8 Bf[16];
#pragma unroll
    for (int t = 0; t < 8; ++t) {
        const short* p = abf + ((k * MPC + t * 16 + li) * DIMD + quad * 8);
        Bf[t * 2 + 0] = *(const s16x8*)(p);
        Bf[t * 2 + 1] = *(const s16x8*)(p + 32);
    }
    float eb[8];
#pragma unroll
    for (int t = 0; t < 8; ++t) eb[t] = ebp[k * MPC + t * 16 + li];
    const float sk2 = s[k] * LN2;

    // stager mapping (threads 0..127): chunk t = (dc*64 + quad*16 + li), 8 floats of x
    const int  sli   = tid & 15;
    const int  squad = (tid >> 4) & 3;
    const int  sdc   = (tid >> 6) & 1;
    const bool stager = (tid < 128);

    float4 g0, g1;
    if (stager) {
        const float* gp = x + (r_base + sli) * DIMD + sdc * 32 + squad * 8;
        g0 = *(const float4*)(gp);
        g1 = *(const float4*)(gp + 4);
        __hip_bfloat162 p0 = __float22bfloat162_rn(make_float2(g0.x, g0.y));
        __hip_bfloat162 p1 = __float22bfloat162_rn(make_float2(g0.z, g0.w));
        __hip_bfloat162 p2 = __float22bfloat162_rn(make_float2(g1.x, g1.y));
        __hip_bfloat162 p3 = __float22bfloat162_rn(make_float2(g1.z, g1.w));
        int4 pk;
        pk.x = (int)b2u(p0); pk.y = (int)b2u(p1); pk.z = (int)b2u(p2); pk.w = (int)b2u(p3);
        xs4[0][tid] = pk;
    }

    for (int g = 0; g < 8; ++g) {
        __syncthreads();  // xs4[g&1] ready; previous reads of other buffer complete
        const int cur = g & 1;

        // issue next group's global loads early (land during MFMA+epilogue)
        if (stager && g + 1 < 8) {
            const float* gp = x + (r_base + (g + 1) * 16 + sli) * DIMD + sdc * 32 + squad * 8;
            g0 = *(const float4*)(gp);
            g1 = *(const float4*)(gp + 4);
        }

        // A fragments from LDS (fragment-ordered: offset = dc*512 + l*8 shorts)
        const short* xsp = (const short*)&xs4[cur][0];
        s16x8 a0 = *(const s16x8*)(xsp + l * 8);
        s16x8 a1 = *(const s16x8*)(xsp + 512 + l * 8);

        f32x4 acc[8];
#pragma unroll
        for (int t = 0; t < 8; ++t) {
            f32x4 z = {0.f, 0.f, 0.f, 0.f};
            acc[t] = __builtin_amdgcn_mfma_f32_16x16x32_bf16(a0, Bf[t * 2 + 0], z, 0, 0, 0);
            acc[t] = __builtin_amdgcn_mfma_f32_16x16x32_bf16(a1, Bf[t * 2 + 1], acc[t], 0, 0, 0);
        }

        // epilogue: lse in log2 domain, sum = sum_m exp(b_m) * 2^(score*log2e)
        const int r0 = r_base + g * 16;
#pragma unroll
        for (int j = 0; j < 4; ++j) {
            float sum = 0.f;
#pragma unroll
            for (int t = 0; t < 8; ++t)
                sum = fmaf(eb[t], __builtin_amdgcn_exp2f(acc[t][j]), sum);
            sum += __shfl_xor(sum, 1);
            sum += __shfl_xor(sum, 2);
            sum += __shfl_xor(sum, 4);
            sum += __shfl_xor(sum, 8);
            if (li == 0) {
                float lse2 = __log2f(sum);
                atomicAdd(&out[r0 + quad * 4 + j], sk2 * lse2);
            }
        }

        // convert+write next group's staged data into the other buffer
        if (stager && g + 1 < 8) {
            __hip_bfloat162 p0 = __float22bfloat162_rn(make_float2(g0.x, g0.y));
            __hip_bfloat162 p1 = __float22bfloat162_rn(make_float2(g0.z, g0.w));
            __hip_bfloat162 p2 = __float22bfloat162_rn(make_float2(g1.x, g1.y));
            __hip_bfloat162 p3 = __float22bfloat162_rn(make_float2(g1.z, g1.w));
            int4 pk;
            pk.x = (int)b2u(p0); pk.y = (int)b2u(p1); pk.z = (int)b2u(p2); pk.w = (int)b2u(p3);
            xs4[1 - cur][tid] = pk;
        }
    }
}

extern "C" void kernel_launch(void* const* d_in, const int* in_sizes, int n_in,
                              void* d_out, int out_size, void* d_ws, size_t ws_size,
                              hipStream_t stream) {
    const float* x = (const float*)d_in[0];
    const float* s = (const float*)d_in[1];
    const float* a = (const float*)d_in[2];
    const float* b = (const float*)d_in[3];
    float* out = (float*)d_out;

    short* abf = (short*)d_ws;
    float* eb  = (float*)((char*)d_ws + (size_t)KEXP * MPC * DIMD * 2);  // 256 KB offset

    hipMemsetAsync(d_out, 0, (size_t)NROWS * sizeof(float), stream);
    prep_kernel<<<129, 256, 0, stream>>>(a, b, abf, eb);

    const int rowblocks = NROWS / 128;           // 1024
    moe_lse_kernel<<<rowblocks * 4, 256, 0, stream>>>(x, s, abf, eb, out);
}

// Round 2
// 127.747 us; speedup vs baseline: 1.3441x; 1.3441x over previous
//
#include <hip/hip_runtime.h>
#include <hip/hip_bf16.h>

#define NROWS 131072
#define KEXP 16
#define MPC 128
#define DIMD 64

typedef float f32x4 __attribute__((ext_vector_type(4)));
typedef short s16x8 __attribute__((ext_vector_type(8)));

#define L2E 1.4426950408889634f
#define LN2 0.6931471805599453f

static __device__ inline unsigned int b2u(__hip_bfloat162 h) {
    union { __hip_bfloat162 h; unsigned int u; } c;
    c.h = h;
    return c.u;
}

// prep: abf = bf16(a * log2e), eb = exp(b)
__global__ void prep_kernel(const float* __restrict__ a, const float* __restrict__ b,
                            short* __restrict__ abf, float* __restrict__ eb) {
    if (blockIdx.x < 128) {
        int i = (blockIdx.x * 256 + threadIdx.x) * 4;
        float4 v = *(const float4*)(a + i);
        __hip_bfloat162 p0 = __float22bfloat162_rn(make_float2(v.x * L2E, v.y * L2E));
        __hip_bfloat162 p1 = __float22bfloat162_rn(make_float2(v.z * L2E, v.w * L2E));
        uint2 u;
        u.x = b2u(p0);
        u.y = b2u(p1);
        *(uint2*)(abf + i) = u;
    } else {
        for (int r = threadIdx.x; r < KEXP * MPC; r += 256)
            eb[r] = __expf(b[r]);
    }
}

// Block = 256 threads (4 waves), handles 128 rows x 4 experts (expert-group eg).
// Stage all 128 rows of x as bf16 fragments into LDS once (1 barrier), then each
// wave computes its expert over 8 row-groups with NO barriers (ds_read+MFMA+exp).
// Per-wave weighted lse -> LDS partials -> one barrier -> coalesced store to ws.
// No atomics; combine kernel sums the 4 expert-group slices.
__global__ __launch_bounds__(256, 3)
void moe_lse_kernel(const float* __restrict__ x, const float* __restrict__ s,
                    const short* __restrict__ abf, const float* __restrict__ ebp,
                    float* __restrict__ lsew) {
    __shared__ int4 xbuf[1024];          // 16 KB: [g(8)][dc(2)][l(64)] 16B frags
    __shared__ float partial[4][128];    // 2 KB per-wave row results

    const int tid  = threadIdx.x;
    const int w    = tid >> 6;
    const int l    = tid & 63;
    const int li   = l & 15;
    const int quad = l >> 4;

    const int eg     = blockIdx.x & 3;
    const int rb     = blockIdx.x >> 2;
    const int k      = eg * 4 + w;
    const int r_base = rb * 128;

    // persistent B fragments: lane holds m = t*16+li, d = dc*32 + quad*8 .. +7
    s16x8 Bf[16];
#pragma unroll
    for (int t = 0; t < 8; ++t) {
        const short* p = abf + ((k * MPC + t * 16 + li) * DIMD + quad * 8);
        Bf[t * 2 + 0] = *(const s16x8*)(p);
        Bf[t * 2 + 1] = *(const s16x8*)(p + 32);
    }
    float eb[8];
#pragma unroll
    for (int t = 0; t < 8; ++t) eb[t] = ebp[k * MPC + t * 16 + li];
    const float sk2 = s[k] * LN2;

    // stage 128 rows of x into LDS in fragment order (4 entries per thread)
#pragma unroll
    for (int i = 0; i < 4; ++i) {
        const int e   = i * 256 + tid;
        const int g   = e >> 7;
        const int dc  = (e >> 6) & 1;
        const int ll  = e & 63;
        const int sli = ll & 15;
        const int sq  = ll >> 4;
        const float* gp = x + (r_base + g * 16 + sli) * DIMD + dc * 32 + sq * 8;
        float4 f0 = *(const float4*)(gp);
        float4 f1 = *(const float4*)(gp + 4);
        __hip_bfloat162 p0 = __float22bfloat162_rn(make_float2(f0.x, f0.y));
        __hip_bfloat162 p1 = __float22bfloat162_rn(make_float2(f0.z, f0.w));
        __hip_bfloat162 p2 = __float22bfloat162_rn(make_float2(f1.x, f1.y));
        __hip_bfloat162 p3 = __float22bfloat162_rn(make_float2(f1.z, f1.w));
        int4 pk;
        pk.x = (int)b2u(p0); pk.y = (int)b2u(p1); pk.z = (int)b2u(p2); pk.w = (int)b2u(p3);
        xbuf[e] = pk;
    }
    __syncthreads();

    // each wave independently: 8 groups of 16 rows, no barriers
    for (int g = 0; g < 8; ++g) {
        const short* xsp = (const short*)xbuf + g * 1024;
        s16x8 a0 = *(const s16x8*)(xsp + l * 8);
        s16x8 a1 = *(const s16x8*)(xsp + 512 + l * 8);

        f32x4 acc[8];
#pragma unroll
        for (int t = 0; t < 8; ++t) {
            f32x4 z = {0.f, 0.f, 0.f, 0.f};
            acc[t] = __builtin_amdgcn_mfma_f32_16x16x32_bf16(a0, Bf[t * 2 + 0], z, 0, 0, 0);
            acc[t] = __builtin_amdgcn_mfma_f32_16x16x32_bf16(a1, Bf[t * 2 + 1], acc[t], 0, 0, 0);
        }

        // lse in log2 domain; butterfly leaves sums on all 16 lanes of each quad
        float sums[4];
#pragma unroll
        for (int j = 0; j < 4; ++j) {
            float sum = 0.f;
#pragma unroll
            for (int t = 0; t < 8; ++t)
                sum = fmaf(eb[t], __builtin_amdgcn_exp2f(acc[t][j]), sum);
            sum += __shfl_xor(sum, 1);
            sum += __shfl_xor(sum, 2);
            sum += __shfl_xor(sum, 4);
            sum += __shfl_xor(sum, 8);
            sums[j] = sum;
        }
        const int m3 = li & 3;
        float v = sums[0];
        v = (m3 == 1) ? sums[1] : v;
        v = (m3 == 2) ? sums[2] : v;
        v = (m3 == 3) ? sums[3] : v;
        float r = sk2 * __log2f(v);
        if (li < 4) partial[w][g * 16 + quad * 4 + li] = r;
    }
    __syncthreads();

    if (tid < 128) {
        float sv = partial[0][tid] + partial[1][tid] + partial[2][tid] + partial[3][tid];
        lsew[eg * NROWS + r_base + tid] = sv;
    }
}

// out[n] = sum over 4 expert-group slices
__global__ void combine_kernel(const float* __restrict__ lsew, float* __restrict__ out) {
    const int i = blockIdx.x * 256 + threadIdx.x;  // f32x4 index
    const f32x4* p = (const f32x4*)lsew;
    const int stride = NROWS / 4;
    f32x4 v = p[i] + p[stride + i] + p[2 * stride + i] + p[3 * stride + i];
    ((f32x4*)out)[i] = v;
}

extern "C" void kernel_launch(void* const* d_in, const int* in_sizes, int n_in,
                              void* d_out, int out_size, void* d_ws, size_t ws_size,
                              hipStream_t stream) {
    const float* x = (const float*)d_in[0];
    const float* s = (const float*)d_in[1];
    const float* a = (const float*)d_in[2];
    const float* b = (const float*)d_in[3];
    float* out = (float*)d_out;

    short* abf  = (short*)d_ws;                                        // 256 KB
    float* eb   = (float*)((char*)d_ws + (size_t)KEXP * MPC * DIMD * 2);  // 8 KB
    float* lsew = (float*)((char*)d_ws + 264 * 1024);                  // 4 x N floats = 2 MB

    prep_kernel<<<129, 256, 0, stream>>>(a, b, abf, eb);

    const int rowblocks = NROWS / 128;  // 1024
    moe_lse_kernel<<<rowblocks * 4, 256, 0, stream>>>(x, s, abf, eb, lsew);

    combine_kernel<<<NROWS / 1024, 256, 0, stream>>>(lsew, out);
}